// Round 18
// baseline (224.527 us; speedup 1.0000x reference)
//
#include <hip/hip_runtime.h>
#include <hip/hip_fp16.h>
#include <math.h>

#define NNODES 100000
#define BSHIFT 7
#define BSIZE 128
#define NBUCK ((NNODES + BSIZE - 1) >> BSHIFT)  // 782
#define SCAT_BLOCKS 1024
#define CHUNKCAP 1664
#define CAPSHIFT 12
#define BCAP (1 << CAPSHIFT)

// ---------- fused single-pass bucket scatter ----------
__global__ __launch_bounds__(256) void k_scatter_fused(const int* __restrict__ src, const int* __restrict__ dst,
                                                       int* __restrict__ bcur, int* __restrict__ staging,
                                                       int E, int chunk) {
    __shared__ int epack[CHUNKCAP];
    __shared__ unsigned short ebuck[CHUNKCAP];
    __shared__ int hist[NBUCK];
    __shared__ int lcur[NBUCK];
    int t = threadIdx.x;
    for (int k = t; k < NBUCK; k += 256) hist[k] = 0;
    __syncthreads();
    int c0 = blockIdx.x * chunk;
    int c1 = min(E, c0 + chunk);
    int n = c1 - c0;
    if (n <= 0) return;
    int n4 = n >> 2;
    const int4* d4p = (const int4*)(dst + c0);
    const int4* s4p = (const int4*)(src + c0);
    for (int j4 = t; j4 < n4; j4 += 256) {
        int4 d = d4p[j4];
        int4 s = s4p[j4];
        int j = j4 << 2;
        epack[j + 0] = (s.x << BSHIFT) | (d.x & (BSIZE - 1));
        epack[j + 1] = (s.y << BSHIFT) | (d.y & (BSIZE - 1));
        epack[j + 2] = (s.z << BSHIFT) | (d.z & (BSIZE - 1));
        epack[j + 3] = (s.w << BSHIFT) | (d.w & (BSIZE - 1));
        ebuck[j + 0] = (unsigned short)(d.x >> BSHIFT);
        ebuck[j + 1] = (unsigned short)(d.y >> BSHIFT);
        ebuck[j + 2] = (unsigned short)(d.z >> BSHIFT);
        ebuck[j + 3] = (unsigned short)(d.w >> BSHIFT);
        atomicAdd(&hist[d.x >> BSHIFT], 1);
        atomicAdd(&hist[d.y >> BSHIFT], 1);
        atomicAdd(&hist[d.z >> BSHIFT], 1);
        atomicAdd(&hist[d.w >> BSHIFT], 1);
    }
    for (int j = (n4 << 2) + t; j < n; j += 256) {
        int d = dst[c0 + j];
        int s = src[c0 + j];
        int b = d >> BSHIFT;
        epack[j] = (s << BSHIFT) | (d & (BSIZE - 1));
        ebuck[j] = (unsigned short)b;
        atomicAdd(&hist[b], 1);
    }
    __syncthreads();
    for (int k = t; k < NBUCK; k += 256) {
        int c = hist[k];
        int ofs = c ? atomicAdd(&bcur[k], c) : 0;
        lcur[k] = (k << CAPSHIFT) + ofs;
    }
    __syncthreads();
    for (int j = t; j < n; j += 256) {
        int pos = atomicAdd(&lcur[ebuck[j]], 1);
        staging[pos] = epack[j];
    }
}

// ---------- per-bucket CSR, LDS-staged ----------
__global__ __launch_bounds__(256) void k_bucket_csr(const int* __restrict__ staging, const int* __restrict__ bcur,
                                                    int* __restrict__ rowptr, int* __restrict__ rowend,
                                                    int* __restrict__ ssoff, float* __restrict__ dinv, int N) {
    __shared__ int seg[BCAP];
    __shared__ int lcnt[BSIZE], lpre[BSIZE];
    int b = blockIdx.x, t = threadIdx.x;
    int node0 = b << BSHIFT;
    int bbase = b << CAPSHIFT;
    int cnt = bcur[b];
    for (int j = t; j < cnt; j += 256) seg[j] = staging[bbase + j];
    if (t < BSIZE) lcnt[t] = 0;
    __syncthreads();
    for (int j = t; j < cnt; j += 256)
        atomicAdd(&lcnt[seg[j] & (BSIZE - 1)], 1);
    __syncthreads();
    if (t < BSIZE) lpre[t] = lcnt[t];
    __syncthreads();
    #pragma unroll
    for (int off = 1; off < BSIZE; off <<= 1) {
        int u = 0;
        if (t < BSIZE && t >= off) u = lpre[t - off];
        __syncthreads();
        if (t < BSIZE) lpre[t] += u;
        __syncthreads();
    }
    if (t < BSIZE) {
        int node = node0 + t;
        if (node < N) {
            int beg = bbase + lpre[t] - lcnt[t];
            rowptr[node] = beg;
            rowend[node] = beg + lcnt[t];
            dinv[node] = rsqrtf((float)(lcnt[t] + 1));
        }
        lpre[t] -= lcnt[t];
    }
    __syncthreads();
    for (int j = t; j < cnt; j += 256) {
        int p = seg[j];
        int pos = atomicAdd(&lpre[p & (BSIZE - 1)], 1);
        ssoff[bbase + pos] = (p >> BSHIFT) << 7;
    }
}

// ---------- G(half) = dinv[i] * (X @ W): templated on input type ----------
template<bool HALF_IN>
__global__ __launch_bounds__(256) void k_transform3(const void* __restrict__ Xv, const float* __restrict__ W,
                                                    const float* __restrict__ dinv, __half* __restrict__ Gh, int N) {
    __shared__ float4 Xs[2048];
    __shared__ float dinvs[128];
    int t = threadIdx.x;
    int lane = t & 63;
    int node0 = blockIdx.x << 7;
    {
        int lim = N << 4;
        int gbase = node0 << 4;
        if (HALF_IN) {
            const int2* X2 = (const int2*)Xv;
            #pragma unroll
            for (int j = 0; j < 8; j++) {
                int f = j * 256 + t;
                int gi = gbase + f;
                float4 v = make_float4(0.f, 0.f, 0.f, 0.f);
                if (gi < lim) {
                    int2 raw = X2[gi];
                    const __half2* hp = (const __half2*)&raw;
                    float2 f01 = __half22float2(hp[0]);
                    float2 f23 = __half22float2(hp[1]);
                    v = make_float4(f01.x, f01.y, f23.x, f23.y);
                }
                Xs[f] = v;
            }
        } else {
            const float4* X4 = (const float4*)Xv;
            #pragma unroll
            for (int j = 0; j < 8; j++) {
                int f = j * 256 + t;
                int gi = gbase + f;
                Xs[f] = (gi < lim) ? X4[gi] : make_float4(0.f, 0.f, 0.f, 0.f);
            }
        }
    }
    if (t < 128) {
        int nd = node0 + t;
        dinvs[t] = (nd < N) ? dinv[nd] : 0.f;
    }
    float w[64];
    #pragma unroll
    for (int k = 0; k < 64; k++) w[k] = W[k * 64 + lane];
    __syncthreads();
    int woff = (t >> 6) * 32;
    for (int nn = 0; nn < 32; nn += 4) {
        const float4* r0 = &Xs[(woff + nn + 0) * 16];
        const float4* r1 = &Xs[(woff + nn + 1) * 16];
        const float4* r2 = &Xs[(woff + nn + 2) * 16];
        const float4* r3 = &Xs[(woff + nn + 3) * 16];
        float a0 = 0.f, a1 = 0.f, a2 = 0.f, a3 = 0.f;
        #pragma unroll
        for (int kq = 0; kq < 16; kq++) {
            float4 xa = r0[kq];
            float4 xb = r1[kq];
            float4 xc = r2[kq];
            float4 xd = r3[kq];
            a0 = fmaf(xa.x, w[4*kq+0], a0); a0 = fmaf(xa.y, w[4*kq+1], a0);
            a0 = fmaf(xa.z, w[4*kq+2], a0); a0 = fmaf(xa.w, w[4*kq+3], a0);
            a1 = fmaf(xb.x, w[4*kq+0], a1); a1 = fmaf(xb.y, w[4*kq+1], a1);
            a1 = fmaf(xb.z, w[4*kq+2], a1); a1 = fmaf(xb.w, w[4*kq+3], a1);
            a2 = fmaf(xc.x, w[4*kq+0], a2); a2 = fmaf(xc.y, w[4*kq+1], a2);
            a2 = fmaf(xc.z, w[4*kq+2], a2); a2 = fmaf(xc.w, w[4*kq+3], a2);
            a3 = fmaf(xd.x, w[4*kq+0], a3); a3 = fmaf(xd.y, w[4*kq+1], a3);
            a3 = fmaf(xd.z, w[4*kq+2], a3); a3 = fmaf(xd.w, w[4*kq+3], a3);
        }
        int nb = node0 + woff + nn;
        float d0 = dinvs[woff+nn+0], d1 = dinvs[woff+nn+1];
        float d2 = dinvs[woff+nn+2], d3 = dinvs[woff+nn+3];
        if (nb + 3 < N) {
            Gh[(size_t)(nb+0)*64 + lane] = __float2half(a0 * d0);
            Gh[(size_t)(nb+1)*64 + lane] = __float2half(a1 * d1);
            Gh[(size_t)(nb+2)*64 + lane] = __float2half(a2 * d2);
            Gh[(size_t)(nb+3)*64 + lane] = __float2half(a3 * d3);
        } else {
            if (nb+0 < N) Gh[(size_t)(nb+0)*64 + lane] = __float2half(a0 * d0);
            if (nb+1 < N) Gh[(size_t)(nb+1)*64 + lane] = __float2half(a1 * d1);
            if (nb+2 < N) Gh[(size_t)(nb+2)*64 + lane] = __float2half(a2 * d2);
            if (nb+3 < N) Gh[(size_t)(nb+3)*64 + lane] = __float2half(a3 * d3);
        }
    }
}

// ---------- H(half) = relu(dinv[i] * (G[i] + sum_j G[j]) + b) ----------
__global__ __launch_bounds__(256) void k_agg(const __half* __restrict__ G, const int* __restrict__ rowptr,
                                             const int* __restrict__ rowend, const int* __restrict__ ssoff,
                                             const float* __restrict__ dinv, const float* __restrict__ bias,
                                             __half* __restrict__ Hh, int N) {
    int lane = threadIdx.x & 63;
    int wid = threadIdx.x >> 6;
    int sub = lane >> 3;
    int l = lane & 7;
    int i = blockIdx.x * 4 + wid;
    if (i >= N) return;
    const char* Gb = (const char*)G;
    int loff = l << 4;
    int beg = rowptr[i], end = rowend[i];
    float a[8] = {0.f, 0.f, 0.f, 0.f, 0.f, 0.f, 0.f, 0.f};
    int e = beg + sub;
    for (; e + 8 < end; e += 16) {
        int o0 = ssoff[e];
        int o1 = ssoff[e + 8];
        float4 g0 = *(const float4*)(Gb + o0 + loff);
        float4 g1 = *(const float4*)(Gb + o1 + loff);
        const __half2* h0 = (const __half2*)&g0;
        const __half2* h1 = (const __half2*)&g1;
        #pragma unroll
        for (int q = 0; q < 4; q++) {
            float2 f = __half22float2(__hadd2(h0[q], h1[q]));
            a[2 * q]     += f.x;
            a[2 * q + 1] += f.y;
        }
    }
    if (e < end) {
        int o0 = ssoff[e];
        float4 g0 = *(const float4*)(Gb + o0 + loff);
        const __half2* h0 = (const __half2*)&g0;
        #pragma unroll
        for (int q = 0; q < 4; q++) {
            float2 f = __half22float2(h0[q]);
            a[2 * q]     += f.x;
            a[2 * q + 1] += f.y;
        }
    }
    #pragma unroll
    for (int mask = 8; mask <= 32; mask <<= 1) {
        #pragma unroll
        for (int q = 0; q < 8; q++) a[q] += __shfl_xor(a[q], mask);
    }
    if (sub == 0) {
        float4 gs = *(const float4*)(Gb + (i << 7) + loff);
        const __half2* hs = (const __half2*)&gs;
        float di = dinv[i];
        float4 b0v = *(const float4*)(bias + 8 * l);
        float4 b1v = *(const float4*)(bias + 8 * l + 4);
        float bb[8] = {b0v.x, b0v.y, b0v.z, b0v.w, b1v.x, b1v.y, b1v.z, b1v.w};
        float r[8];
        #pragma unroll
        for (int q = 0; q < 4; q++) {
            float2 fs = __half22float2(hs[q]);
            r[2 * q]     = fmaxf(fmaf(di, a[2 * q] + fs.x, bb[2 * q]), 0.f);
            r[2 * q + 1] = fmaxf(fmaf(di, a[2 * q + 1] + fs.y, bb[2 * q + 1]), 0.f);
        }
        int4 ov;
        __half2* op = (__half2*)&ov;
        op[0] = __floats2half2_rn(r[0], r[1]);
        op[1] = __floats2half2_rn(r[2], r[3]);
        op[2] = __floats2half2_rn(r[4], r[5]);
        op[3] = __floats2half2_rn(r[6], r[7]);
        *(int4*)(Hh + (size_t)i * 64 + 8 * l) = ov;
    }
}

// ---------- softmax(H @ Wfc + bfc), H fp16 ----------
__global__ __launch_bounds__(256) void k_fc_softmax(const __half* __restrict__ H, const float* __restrict__ Wfc,
                                                    const float* __restrict__ bfc, float* __restrict__ O, int N) {
    __shared__ float wf[64 * 16];
    __shared__ float bf[16];
    int t = threadIdx.x;
    for (int k = t; k < 1024; k += 256) wf[k] = Wfc[k];
    if (t < 16) bf[t] = bfc[t];
    __syncthreads();
    int gid = blockIdx.x * 256 + t;
    int node = gid >> 4;
    int c = gid & 15;
    if (node >= N) return;
    const int2* hv = (const int2*)(H + (size_t)node * 64);
    float acc = bf[c];
    #pragma unroll
    for (int kk = 0; kk < 16; kk++) {
        int2 raw = hv[kk];
        const __half2* hp = (const __half2*)&raw;
        float2 f01 = __half22float2(hp[0]);
        float2 f23 = __half22float2(hp[1]);
        acc = fmaf(f01.x, wf[(4 * kk + 0) * 16 + c], acc);
        acc = fmaf(f01.y, wf[(4 * kk + 1) * 16 + c], acc);
        acc = fmaf(f23.x, wf[(4 * kk + 2) * 16 + c], acc);
        acc = fmaf(f23.y, wf[(4 * kk + 3) * 16 + c], acc);
    }
    float m = acc;
    #pragma unroll
    for (int mask = 1; mask < 16; mask <<= 1) m = fmaxf(m, __shfl_xor(m, mask));
    float ex = expf(acc - m);
    float s = ex;
    #pragma unroll
    for (int mask = 1; mask < 16; mask <<= 1) s += __shfl_xor(s, mask);
    O[(size_t)node * 16 + c] = ex / s;
}

extern "C" void kernel_launch(void* const* d_in, const int* in_sizes, int n_in,
                              void* d_out, int out_size, void* d_ws, size_t ws_size,
                              hipStream_t stream) {
    const float* x   = (const float*)d_in[0];
    const int*   ei  = (const int*)d_in[1];
    const float* W1  = (const float*)d_in[2];
    const float* b1  = (const float*)d_in[3];
    const float* W2  = (const float*)d_in[4];
    const float* b2  = (const float*)d_in[5];
    const float* Wfc = (const float*)d_in[6];
    const float* bfc = (const float*)d_in[7];
    float* out = (float*)d_out;
    const int N = NNODES;
    const int E = in_sizes[1] / 2;

    char* ws = (char*)d_ws;
    size_t off = 0;
    auto take = [&](size_t bytes) {
        char* p = ws + off;
        off = (off + bytes + 255) & ~(size_t)255;
        return p;
    };
    int*    staging = (int*)take((size_t)NBUCK * BCAP * 4);
    int*    ssoff   = (int*)take((size_t)NBUCK * BCAP * 4);
    __half* Gh      = (__half*)take((size_t)N * 64 * 2);
    __half* Hh      = (__half*)take((size_t)N * 64 * 2);
    int*    rowptr  = (int*)take((size_t)N * 4);
    int*    rowend  = (int*)take((size_t)N * 4);
    float*  dinv    = (float*)take((size_t)N * 4);
    int*    bcur    = (int*)take((size_t)NBUCK * 4);

    const int* e_src = ei;
    const int* e_dst = ei + E;

    int chunk = ((E + SCAT_BLOCKS - 1) / SCAT_BLOCKS + 3) & ~3;  // mult of 4, <= CHUNKCAP
    hipMemsetAsync(bcur, 0, (size_t)NBUCK * 4, stream);
    k_scatter_fused<<<SCAT_BLOCKS, 256, 0, stream>>>(e_src, e_dst, bcur, staging, E, chunk);
    k_bucket_csr<<<NBUCK, 256, 0, stream>>>(staging, bcur, rowptr, rowend, ssoff, dinv, N);
    k_transform3<false><<<(N + 127) / 128, 256, 0, stream>>>(x, W1, dinv, Gh, N);
    k_agg<<<(N + 3) / 4, 256, 0, stream>>>(Gh, rowptr, rowend, ssoff, dinv, b1, Hh, N);
    k_transform3<true><<<(N + 127) / 128, 256, 0, stream>>>(Hh, W2, dinv, Gh, N);
    k_agg<<<(N + 3) / 4, 256, 0, stream>>>(Gh, rowptr, rowend, ssoff, dinv, b2, Hh, N);
    k_fc_softmax<<<(N * 16 + 255) / 256, 256, 0, stream>>>(Hh, Wfc, bfc, out, N);
}

// Round 19
// 208.798 us; speedup vs baseline: 1.0753x; 1.0753x over previous
//
#include <hip/hip_runtime.h>
#include <hip/hip_fp16.h>
#include <math.h>

#define NNODES 100000
#define BSHIFT 7
#define BSIZE 128
#define NBUCK ((NNODES + BSIZE - 1) >> BSHIFT)  // 782
#define SCAT_BLOCKS 512
#define CHUNKCAP 3328
#define CAPSHIFT 12
#define BCAP (1 << CAPSHIFT)

// ---------- fused single-pass bucket scatter ----------
__global__ __launch_bounds__(256) void k_scatter_fused(const int* __restrict__ src, const int* __restrict__ dst,
                                                       int* __restrict__ bcur, int* __restrict__ staging,
                                                       int E, int chunk) {
    __shared__ int epack[CHUNKCAP];
    __shared__ unsigned short ebuck[CHUNKCAP];
    __shared__ int hist[NBUCK];
    __shared__ int lcur[NBUCK];
    int t = threadIdx.x;
    for (int k = t; k < NBUCK; k += 256) hist[k] = 0;
    __syncthreads();
    int c0 = blockIdx.x * chunk;
    int c1 = min(E, c0 + chunk);
    int n = c1 - c0;
    if (n <= 0) return;
    int n4 = n >> 2;
    const int4* d4p = (const int4*)(dst + c0);
    const int4* s4p = (const int4*)(src + c0);
    for (int j4 = t; j4 < n4; j4 += 256) {
        int4 d = d4p[j4];
        int4 s = s4p[j4];
        int j = j4 << 2;
        epack[j + 0] = (s.x << BSHIFT) | (d.x & (BSIZE - 1));
        epack[j + 1] = (s.y << BSHIFT) | (d.y & (BSIZE - 1));
        epack[j + 2] = (s.z << BSHIFT) | (d.z & (BSIZE - 1));
        epack[j + 3] = (s.w << BSHIFT) | (d.w & (BSIZE - 1));
        ebuck[j + 0] = (unsigned short)(d.x >> BSHIFT);
        ebuck[j + 1] = (unsigned short)(d.y >> BSHIFT);
        ebuck[j + 2] = (unsigned short)(d.z >> BSHIFT);
        ebuck[j + 3] = (unsigned short)(d.w >> BSHIFT);
        atomicAdd(&hist[d.x >> BSHIFT], 1);
        atomicAdd(&hist[d.y >> BSHIFT], 1);
        atomicAdd(&hist[d.z >> BSHIFT], 1);
        atomicAdd(&hist[d.w >> BSHIFT], 1);
    }
    for (int j = (n4 << 2) + t; j < n; j += 256) {
        int d = dst[c0 + j];
        int s = src[c0 + j];
        int b = d >> BSHIFT;
        epack[j] = (s << BSHIFT) | (d & (BSIZE - 1));
        ebuck[j] = (unsigned short)b;
        atomicAdd(&hist[b], 1);
    }
    __syncthreads();
    for (int k = t; k < NBUCK; k += 256) {
        int c = hist[k];
        int ofs = c ? atomicAdd(&bcur[k], c) : 0;
        lcur[k] = (k << CAPSHIFT) + ofs;
    }
    __syncthreads();
    for (int j = t; j < n; j += 256) {
        int pos = atomicAdd(&lcur[ebuck[j]], 1);
        staging[pos] = epack[j];
    }
}

// ---------- per-bucket CSR, LDS-staged ----------
__global__ __launch_bounds__(256) void k_bucket_csr(const int* __restrict__ staging, const int* __restrict__ bcur,
                                                    int* __restrict__ rowptr, int* __restrict__ rowend,
                                                    int* __restrict__ ssoff, float* __restrict__ dinv, int N) {
    __shared__ int seg[BCAP];
    __shared__ int lcnt[BSIZE], lpre[BSIZE];
    int b = blockIdx.x, t = threadIdx.x;
    int node0 = b << BSHIFT;
    int bbase = b << CAPSHIFT;
    int cnt = bcur[b];
    for (int j = t; j < cnt; j += 256) seg[j] = staging[bbase + j];
    if (t < BSIZE) lcnt[t] = 0;
    __syncthreads();
    for (int j = t; j < cnt; j += 256)
        atomicAdd(&lcnt[seg[j] & (BSIZE - 1)], 1);
    __syncthreads();
    if (t < BSIZE) lpre[t] = lcnt[t];
    __syncthreads();
    #pragma unroll
    for (int off = 1; off < BSIZE; off <<= 1) {
        int u = 0;
        if (t < BSIZE && t >= off) u = lpre[t - off];
        __syncthreads();
        if (t < BSIZE) lpre[t] += u;
        __syncthreads();
    }
    if (t < BSIZE) {
        int node = node0 + t;
        if (node < N) {
            int beg = bbase + lpre[t] - lcnt[t];
            rowptr[node] = beg;
            rowend[node] = beg + lcnt[t];
            dinv[node] = rsqrtf((float)(lcnt[t] + 1));
        }
        lpre[t] -= lcnt[t];
    }
    __syncthreads();
    for (int j = t; j < cnt; j += 256) {
        int p = seg[j];
        int pos = atomicAdd(&lpre[p & (BSIZE - 1)], 1);
        ssoff[bbase + pos] = (p >> BSHIFT) << 7;
    }
}

// ---------- G(half) = dinv[i] * (X @ W): templated on input type ----------
template<bool HALF_IN>
__global__ __launch_bounds__(256) void k_transform3(const void* __restrict__ Xv, const float* __restrict__ W,
                                                    const float* __restrict__ dinv, __half* __restrict__ Gh, int N) {
    __shared__ float4 Xs[2048];
    __shared__ float dinvs[128];
    int t = threadIdx.x;
    int lane = t & 63;
    int node0 = blockIdx.x << 7;
    {
        int lim = N << 4;
        int gbase = node0 << 4;
        if (HALF_IN) {
            const int2* X2 = (const int2*)Xv;
            #pragma unroll
            for (int j = 0; j < 8; j++) {
                int f = j * 256 + t;
                int gi = gbase + f;
                float4 v = make_float4(0.f, 0.f, 0.f, 0.f);
                if (gi < lim) {
                    int2 raw = X2[gi];
                    const __half2* hp = (const __half2*)&raw;
                    float2 f01 = __half22float2(hp[0]);
                    float2 f23 = __half22float2(hp[1]);
                    v = make_float4(f01.x, f01.y, f23.x, f23.y);
                }
                Xs[f] = v;
            }
        } else {
            const float4* X4 = (const float4*)Xv;
            #pragma unroll
            for (int j = 0; j < 8; j++) {
                int f = j * 256 + t;
                int gi = gbase + f;
                Xs[f] = (gi < lim) ? X4[gi] : make_float4(0.f, 0.f, 0.f, 0.f);
            }
        }
    }
    if (t < 128) {
        int nd = node0 + t;
        dinvs[t] = (nd < N) ? dinv[nd] : 0.f;
    }
    float w[64];
    #pragma unroll
    for (int k = 0; k < 64; k++) w[k] = W[k * 64 + lane];
    __syncthreads();
    int woff = (t >> 6) * 32;
    for (int nn = 0; nn < 32; nn += 4) {
        const float4* r0 = &Xs[(woff + nn + 0) * 16];
        const float4* r1 = &Xs[(woff + nn + 1) * 16];
        const float4* r2 = &Xs[(woff + nn + 2) * 16];
        const float4* r3 = &Xs[(woff + nn + 3) * 16];
        float a0 = 0.f, a1 = 0.f, a2 = 0.f, a3 = 0.f;
        #pragma unroll
        for (int kq = 0; kq < 16; kq++) {
            float4 xa = r0[kq];
            float4 xb = r1[kq];
            float4 xc = r2[kq];
            float4 xd = r3[kq];
            a0 = fmaf(xa.x, w[4*kq+0], a0); a0 = fmaf(xa.y, w[4*kq+1], a0);
            a0 = fmaf(xa.z, w[4*kq+2], a0); a0 = fmaf(xa.w, w[4*kq+3], a0);
            a1 = fmaf(xb.x, w[4*kq+0], a1); a1 = fmaf(xb.y, w[4*kq+1], a1);
            a1 = fmaf(xb.z, w[4*kq+2], a1); a1 = fmaf(xb.w, w[4*kq+3], a1);
            a2 = fmaf(xc.x, w[4*kq+0], a2); a2 = fmaf(xc.y, w[4*kq+1], a2);
            a2 = fmaf(xc.z, w[4*kq+2], a2); a2 = fmaf(xc.w, w[4*kq+3], a2);
            a3 = fmaf(xd.x, w[4*kq+0], a3); a3 = fmaf(xd.y, w[4*kq+1], a3);
            a3 = fmaf(xd.z, w[4*kq+2], a3); a3 = fmaf(xd.w, w[4*kq+3], a3);
        }
        int nb = node0 + woff + nn;
        float d0 = dinvs[woff+nn+0], d1 = dinvs[woff+nn+1];
        float d2 = dinvs[woff+nn+2], d3 = dinvs[woff+nn+3];
        if (nb + 3 < N) {
            Gh[(size_t)(nb+0)*64 + lane] = __float2half(a0 * d0);
            Gh[(size_t)(nb+1)*64 + lane] = __float2half(a1 * d1);
            Gh[(size_t)(nb+2)*64 + lane] = __float2half(a2 * d2);
            Gh[(size_t)(nb+3)*64 + lane] = __float2half(a3 * d3);
        } else {
            if (nb+0 < N) Gh[(size_t)(nb+0)*64 + lane] = __float2half(a0 * d0);
            if (nb+1 < N) Gh[(size_t)(nb+1)*64 + lane] = __float2half(a1 * d1);
            if (nb+2 < N) Gh[(size_t)(nb+2)*64 + lane] = __float2half(a2 * d2);
            if (nb+3 < N) Gh[(size_t)(nb+3)*64 + lane] = __float2half(a3 * d3);
        }
    }
}

// ---------- H(half) = relu(dinv[i] * (G[i] + sum_j G[j]) + b) ----------
__global__ __launch_bounds__(256) void k_agg(const __half* __restrict__ G, const int* __restrict__ rowptr,
                                             const int* __restrict__ rowend, const int* __restrict__ ssoff,
                                             const float* __restrict__ dinv, const float* __restrict__ bias,
                                             __half* __restrict__ Hh, int N) {
    int lane = threadIdx.x & 63;
    int wid = threadIdx.x >> 6;
    int sub = lane >> 3;
    int l = lane & 7;
    int i = blockIdx.x * 4 + wid;
    if (i >= N) return;
    const char* Gb = (const char*)G;
    int loff = l << 4;
    int beg = rowptr[i], end = rowend[i];
    float a[8] = {0.f, 0.f, 0.f, 0.f, 0.f, 0.f, 0.f, 0.f};
    int e = beg + sub;
    for (; e + 8 < end; e += 16) {
        int o0 = ssoff[e];
        int o1 = ssoff[e + 8];
        float4 g0 = *(const float4*)(Gb + o0 + loff);
        float4 g1 = *(const float4*)(Gb + o1 + loff);
        const __half2* h0 = (const __half2*)&g0;
        const __half2* h1 = (const __half2*)&g1;
        #pragma unroll
        for (int q = 0; q < 4; q++) {
            float2 f = __half22float2(__hadd2(h0[q], h1[q]));
            a[2 * q]     += f.x;
            a[2 * q + 1] += f.y;
        }
    }
    if (e < end) {
        int o0 = ssoff[e];
        float4 g0 = *(const float4*)(Gb + o0 + loff);
        const __half2* h0 = (const __half2*)&g0;
        #pragma unroll
        for (int q = 0; q < 4; q++) {
            float2 f = __half22float2(h0[q]);
            a[2 * q]     += f.x;
            a[2 * q + 1] += f.y;
        }
    }
    #pragma unroll
    for (int mask = 8; mask <= 32; mask <<= 1) {
        #pragma unroll
        for (int q = 0; q < 8; q++) a[q] += __shfl_xor(a[q], mask);
    }
    if (sub == 0) {
        float4 gs = *(const float4*)(Gb + (i << 7) + loff);
        const __half2* hs = (const __half2*)&gs;
        float di = dinv[i];
        float4 b0v = *(const float4*)(bias + 8 * l);
        float4 b1v = *(const float4*)(bias + 8 * l + 4);
        float bb[8] = {b0v.x, b0v.y, b0v.z, b0v.w, b1v.x, b1v.y, b1v.z, b1v.w};
        float r[8];
        #pragma unroll
        for (int q = 0; q < 4; q++) {
            float2 fs = __half22float2(hs[q]);
            r[2 * q]     = fmaxf(fmaf(di, a[2 * q] + fs.x, bb[2 * q]), 0.f);
            r[2 * q + 1] = fmaxf(fmaf(di, a[2 * q + 1] + fs.y, bb[2 * q + 1]), 0.f);
        }
        int4 ov;
        __half2* op = (__half2*)&ov;
        op[0] = __floats2half2_rn(r[0], r[1]);
        op[1] = __floats2half2_rn(r[2], r[3]);
        op[2] = __floats2half2_rn(r[4], r[5]);
        op[3] = __floats2half2_rn(r[6], r[7]);
        *(int4*)(Hh + (size_t)i * 64 + 8 * l) = ov;
    }
}

// ---------- softmax(H @ Wfc + bfc), H fp16 ----------
__global__ __launch_bounds__(256) void k_fc_softmax(const __half* __restrict__ H, const float* __restrict__ Wfc,
                                                    const float* __restrict__ bfc, float* __restrict__ O, int N) {
    __shared__ float wf[64 * 16];
    __shared__ float bf[16];
    int t = threadIdx.x;
    for (int k = t; k < 1024; k += 256) wf[k] = Wfc[k];
    if (t < 16) bf[t] = bfc[t];
    __syncthreads();
    int gid = blockIdx.x * 256 + t;
    int node = gid >> 4;
    int c = gid & 15;
    if (node >= N) return;
    const int2* hv = (const int2*)(H + (size_t)node * 64);
    float acc = bf[c];
    #pragma unroll
    for (int kk = 0; kk < 16; kk++) {
        int2 raw = hv[kk];
        const __half2* hp = (const __half2*)&raw;
        float2 f01 = __half22float2(hp[0]);
        float2 f23 = __half22float2(hp[1]);
        acc = fmaf(f01.x, wf[(4 * kk + 0) * 16 + c], acc);
        acc = fmaf(f01.y, wf[(4 * kk + 1) * 16 + c], acc);
        acc = fmaf(f23.x, wf[(4 * kk + 2) * 16 + c], acc);
        acc = fmaf(f23.y, wf[(4 * kk + 3) * 16 + c], acc);
    }
    float m = acc;
    #pragma unroll
    for (int mask = 1; mask < 16; mask <<= 1) m = fmaxf(m, __shfl_xor(m, mask));
    float ex = expf(acc - m);
    float s = ex;
    #pragma unroll
    for (int mask = 1; mask < 16; mask <<= 1) s += __shfl_xor(s, mask);
    O[(size_t)node * 16 + c] = ex / s;
}

extern "C" void kernel_launch(void* const* d_in, const int* in_sizes, int n_in,
                              void* d_out, int out_size, void* d_ws, size_t ws_size,
                              hipStream_t stream) {
    const float* x   = (const float*)d_in[0];
    const int*   ei  = (const int*)d_in[1];
    const float* W1  = (const float*)d_in[2];
    const float* b1  = (const float*)d_in[3];
    const float* W2  = (const float*)d_in[4];
    const float* b2  = (const float*)d_in[5];
    const float* Wfc = (const float*)d_in[6];
    const float* bfc = (const float*)d_in[7];
    float* out = (float*)d_out;
    const int N = NNODES;
    const int E = in_sizes[1] / 2;

    char* ws = (char*)d_ws;
    size_t off = 0;
    auto take = [&](size_t bytes) {
        char* p = ws + off;
        off = (off + bytes + 255) & ~(size_t)255;
        return p;
    };
    int*    staging = (int*)take((size_t)NBUCK * BCAP * 4);
    int*    ssoff   = (int*)take((size_t)NBUCK * BCAP * 4);
    __half* Gh      = (__half*)take((size_t)N * 64 * 2);
    __half* Hh      = (__half*)take((size_t)N * 64 * 2);
    int*    rowptr  = (int*)take((size_t)N * 4);
    int*    rowend  = (int*)take((size_t)N * 4);
    float*  dinv    = (float*)take((size_t)N * 4);
    int*    bcur    = (int*)take((size_t)NBUCK * 4);

    const int* e_src = ei;
    const int* e_dst = ei + E;

    int chunk = ((E + SCAT_BLOCKS - 1) / SCAT_BLOCKS + 3) & ~3;  // mult of 4, <= CHUNKCAP
    hipMemsetAsync(bcur, 0, (size_t)NBUCK * 4, stream);
    k_scatter_fused<<<SCAT_BLOCKS, 256, 0, stream>>>(e_src, e_dst, bcur, staging, E, chunk);
    k_bucket_csr<<<NBUCK, 256, 0, stream>>>(staging, bcur, rowptr, rowend, ssoff, dinv, N);
    k_transform3<false><<<(N + 127) / 128, 256, 0, stream>>>(x, W1, dinv, Gh, N);
    k_agg<<<(N + 3) / 4, 256, 0, stream>>>(Gh, rowptr, rowend, ssoff, dinv, b1, Hh, N);
    k_transform3<true><<<(N + 127) / 128, 256, 0, stream>>>(Hh, W2, dinv, Gh, N);
    k_agg<<<(N + 3) / 4, 256, 0, stream>>>(Gh, rowptr, rowend, ssoff, dinv, b2, Hh, N);
    k_fc_softmax<<<(N * 16 + 255) / 256, 256, 0, stream>>>(Hh, Wfc, bfc, out, N);
}